// Round 3
// baseline (406.172 us; speedup 1.0000x reference)
//
#include <hip/hip_runtime.h>
#include <hip/hip_fp16.h>
#include <cstdint>
#include <cstddef>

typedef _Float16 f16;
typedef _Float16 f16x8 __attribute__((ext_vector_type(8)));
typedef _Float16 f16x4 __attribute__((ext_vector_type(4)));
typedef float    f32x4 __attribute__((ext_vector_type(4)));

#define MFMA(a, b, c) __builtin_amdgcn_mfma_f32_16x16x32_f16(a, b, c, 0, 0, 0)

// B=4, S=2048, D=1024, H=16, KS=VS=64, O=1024.
// All four GEMMs are [M=8192, K=1024] x [K=1024, N=1024].

__device__ __forceinline__ void gload_lds16(const f16* g, f16* l) {
    __builtin_amdgcn_global_load_lds(
        (const __attribute__((address_space(1))) void*)g,
        (__attribute__((address_space(3))) void*)l, 16, 0, 0);
}

// --------------------------- fp32 -> fp16 convert ---------------------------
__global__ void k_convert(const float* __restrict__ src, f16* __restrict__ dst, int n4) {
    int i = blockIdx.x * blockDim.x + threadIdx.x;
    int stride = gridDim.x * blockDim.x;
    for (; i < n4; i += stride) {
        float4 v = ((const float4*)src)[i];
        f16x4 h;
        h[0] = (f16)v.x; h[1] = (f16)v.y; h[2] = (f16)v.z; h[3] = (f16)v.w;
        ((f16x4*)dst)[i] = h;
    }
}

// ------------------- weight transpose + convert to fp16 ---------------------
// mode 0: W is [H=16][D=1024][KS=64] -> Wt[n=h*64+ks][k=d]
// mode 1: W is [K=1024][N=1024]      -> Wt[n][k]
__global__ void k_transpose_w(const float* __restrict__ W, f16* __restrict__ Wt, int mode) {
    int idx = blockIdx.x * blockDim.x + threadIdx.x;
    if (idx >= 1024 * 1024) return;
    int n = idx >> 10, d = idx & 1023;
    float v = (mode == 0) ? W[(n >> 6) * 65536 + d * 64 + (n & 63)]
                          : W[d * 1024 + n];
    Wt[idx] = (f16)v;
}

// ------------------------------- GEMM ---------------------------------------
// C[8192][1024] = A[8192][1024] * Bt[1024][1024]^T + bias
// MODE 0: f16 head-major  [(b*16+h)*2048 + s][64]
// MODE 1: f16 vT          [(b*16+h)*64 + d][2048]
// MODE 2: f32 row-major   [M][1024]
template <int MODE>
__global__ __launch_bounds__(256) void k_gemm(const f16* __restrict__ A,
                                              const f16* __restrict__ Bt,
                                              const float* __restrict__ bias,
                                              void* __restrict__ Cout) {
    __shared__ f16 As[128 * 32];   // linear [row][32] (global_load_lds needs linear dest)
    __shared__ f16 Bs[128 * 32];
    const int tid = threadIdx.x;
    const int wid = tid >> 6, lane = tid & 63;
    const int wr = wid >> 1, wc = wid & 1;          // 2x2 waves, 64x64 out each
    const int lr = lane & 15, lg = lane >> 4;
    const int row0 = blockIdx.x * 128, col0 = blockIdx.y * 128;

    f32x4 acc[4][4];
#pragma unroll
    for (int m = 0; m < 4; ++m)
#pragma unroll
        for (int n = 0; n < 4; ++n) acc[m][n] = (f32x4){0.f, 0.f, 0.f, 0.f};

    const int c0 = tid, c1 = tid + 256;             // 16B chunk ids, 512 total
    const int r0 = c0 >> 2, cb0 = (c0 & 3) * 8;
    const int r1 = c1 >> 2, cb1 = (c1 & 3) * 8;

    for (int k0 = 0; k0 < 1024; k0 += 32) {
        __syncthreads();
        gload_lds16(&A[(size_t)(row0 + r0) * 1024 + k0 + cb0], &As[c0 * 8]);
        gload_lds16(&Bt[(size_t)(col0 + r0) * 1024 + k0 + cb0], &Bs[c0 * 8]);
        gload_lds16(&A[(size_t)(row0 + r1) * 1024 + k0 + cb1], &As[c1 * 8]);
        gload_lds16(&Bt[(size_t)(col0 + r1) * 1024 + k0 + cb1], &Bs[c1 * 8]);
        __syncthreads();
        f16x8 af[4], bf[4];
#pragma unroll
        for (int m = 0; m < 4; ++m) af[m] = *(const f16x8*)&As[(wr * 64 + m * 16 + lr) * 32 + lg * 8];
#pragma unroll
        for (int n = 0; n < 4; ++n) bf[n] = *(const f16x8*)&Bs[(wc * 64 + n * 16 + lr) * 32 + lg * 8];
#pragma unroll
        for (int m = 0; m < 4; ++m)
#pragma unroll
            for (int n = 0; n < 4; ++n) acc[m][n] = MFMA(af[m], bf[n], acc[m][n]);
    }

#pragma unroll
    for (int m = 0; m < 4; ++m) {
#pragma unroll
        for (int n = 0; n < 4; ++n) {
            int col = col0 + wc * 64 + n * 16 + lr;
            float bv = bias[col];
#pragma unroll
            for (int r = 0; r < 4; ++r) {
                int row = row0 + wr * 64 + m * 16 + lg * 4 + r;  // C/D: col=lane&15, row=(lane>>4)*4+reg
                float v = acc[m][n][r] + bv;
                if (MODE == 0) {
                    size_t a = ((size_t)((row >> 11) * 16 + (col >> 6)) * 2048 + (row & 2047)) * 64 + (col & 63);
                    ((f16*)Cout)[a] = (f16)v;
                } else if (MODE == 1) {
                    size_t a = ((size_t)((row >> 11) * 16 + (col >> 6)) * 64 + (col & 63)) * 2048 + (row & 2047);
                    ((f16*)Cout)[a] = (f16)v;
                } else {
                    ((float*)Cout)[(size_t)row * 1024 + col] = v;
                }
            }
        }
    }
}

// ------------------------------ attention -----------------------------------
// No LDS. 1024 blocks (XCD-swizzled), 4 waves/block, each wave owns 32 q-rows.
// K/V read directly from global (L2 resident). Swapped QK^T with PERMUTED
// K-row loading: tile t loads K row kt + 8*(lr>>2) + 4*t + (lr&3), so the
// S^T output lands with kpos = kt + 8*lg + (4t+r) on lane (lr,lg) — exactly
// the PV B-fragment k-slot layout (k = lg*8 + j). P never leaves the lane:
// no LDS round-trip, no shfl redistribution. Softmax stats per q-row (= lr)
// via shfl_xor(16/32); defer-max (T13) skips O-rescale on most tiles.
__global__ __launch_bounds__(256) void k_attn(const f16* __restrict__ q,
                                              const f16* __restrict__ k,
                                              const f16* __restrict__ vT,
                                              f16* __restrict__ cat) {
    // swizzle: 16 q-blocks of one (b,h) land on one XCD (K/V L2 locality)
    const int g = blockIdx.x;                 // 0..1023
    const int xcd = g & 7, i = g >> 3;        // i: 0..127
    const int bh = xcd + 8 * (i >> 4);        // bijective, 64 values
    const int qb = i & 15;
    const int b = bh >> 4, h = bh & 15;

    const int tid = threadIdx.x, wid = tid >> 6, lane = tid & 63;
    const int lr = lane & 15, lg = lane >> 4;
    const int qw = qb * 128 + wid * 32;       // this wave's first q-row

    const float SC = 0.125f * 1.44269504089f; // 1/sqrt(64) * log2(e)
    const float THR = 8.0f;                   // defer-max threshold (log2 units)

    // Q fragments (hoisted): B-operand, q-col = lr, d = half*32 + lg*8..
    f16x8 qf[2][2];
#pragma unroll
    for (int qt = 0; qt < 2; ++qt)
#pragma unroll
        for (int hf = 0; hf < 2; ++hf)
            qf[qt][hf] = *(const f16x8*)&q[((size_t)bh * 2048 + qw + qt * 16 + lr) * 64 + hf * 32 + lg * 8];

    // permuted K row base: row kt + 8*(lr>>2) + 4*t + (lr&3)
    const f16* kbase = k + (size_t)bh * 2048 * 64 + (size_t)(8 * (lr >> 2) + (lr & 3)) * 64 + lg * 8;
    const f16* vbase = vT + (size_t)bh * 64 * 2048 + (size_t)lr * 2048 + lg * 8;

    f32x4 o[2][4];
#pragma unroll
    for (int qt = 0; qt < 2; ++qt)
#pragma unroll
        for (int m = 0; m < 4; ++m) o[qt][m] = (f32x4){0.f, 0.f, 0.f, 0.f};
    float m_r[2] = {-1.0e30f, -1.0e30f}, l_r[2] = {0.f, 0.f};

    for (int kt = 0; kt < 2048; kt += 32) {
        // ---- QK^T: st[qt][t]; lane (lr,lg) reg r = S[kpos kt+8lg+4t+r][q qt*16+lr]
        f32x4 st[2][2];
#pragma unroll
        for (int t = 0; t < 2; ++t) {
            const f16* kr = kbase + (size_t)(kt + t * 4) * 64;
            f16x8 k0 = *(const f16x8*)(kr);
            f16x8 k1 = *(const f16x8*)(kr + 32);
#pragma unroll
            for (int qt = 0; qt < 2; ++qt) {
                f32x4 z = (f32x4){0.f, 0.f, 0.f, 0.f};
                z = MFMA(k0, qf[qt][0], z);
                z = MFMA(k1, qf[qt][1], z);
                st[qt][t] = z;
            }
        }

        // ---- online softmax (log2 domain), stats per q-row = lr ----
        float tm[2];
#pragma unroll
        for (int qt = 0; qt < 2; ++qt) {
            float a0 = fmaxf(fmaxf(st[qt][0][0], st[qt][0][1]), fmaxf(st[qt][0][2], st[qt][0][3]));
            float a1 = fmaxf(fmaxf(st[qt][1][0], st[qt][1][1]), fmaxf(st[qt][1][2], st[qt][1][3]));
            float t0 = fmaxf(a0, a1);
            t0 = fmaxf(t0, __shfl_xor(t0, 16, 64));
            t0 = fmaxf(t0, __shfl_xor(t0, 32, 64));
            tm[qt] = t0 * SC;
        }
        bool need = (tm[0] > m_r[0] + THR) || (tm[1] > m_r[1] + THR);
        if (__any(need)) {
#pragma unroll
            for (int qt = 0; qt < 2; ++qt) {
                float m_new = fmaxf(m_r[qt], tm[qt]);
                float alpha = exp2f(m_r[qt] - m_new);
#pragma unroll
                for (int m = 0; m < 4; ++m)
#pragma unroll
                    for (int r = 0; r < 4; ++r) o[qt][m][r] *= alpha;
                l_r[qt] *= alpha;
                m_r[qt] = m_new;
            }
        }

        // ---- P = exp2(st*SC - m): already in B-frag layout, pack in-lane ----
        f16x8 pf[2];
#pragma unroll
        for (int qt = 0; qt < 2; ++qt) {
            float ps = 0.f;
            union { uint32_t u[4]; f16x8 v; } bb;
#pragma unroll
            for (int t = 0; t < 2; ++t)
#pragma unroll
                for (int pr = 0; pr < 2; ++pr) {
                    float p0 = exp2f(st[qt][t][2 * pr] * SC - m_r[qt]);
                    float p1 = exp2f(st[qt][t][2 * pr + 1] * SC - m_r[qt]);
                    ps += p0 + p1;
                    union { f16 h[2]; uint32_t u; } uu;
                    uu.h[0] = (f16)p0; uu.h[1] = (f16)p1;
                    bb.u[t * 2 + pr] = uu.u;    // B-frag word jp = 2t+pr (j = 4t+r)
                }
            ps += __shfl_xor(ps, 16, 64);
            ps += __shfl_xor(ps, 32, 64);
            l_r[qt] += ps;
            pf[qt] = bb.v;
        }

        // ---- PV: O^T[vd][q] += V^T[vd][kpos] * P^T[kpos][q] ----
#pragma unroll
        for (int m = 0; m < 4; ++m) {
            f16x8 vf = *(const f16x8*)(vbase + (size_t)(m * 16) * 2048 + kt);
#pragma unroll
            for (int qt = 0; qt < 2; ++qt) o[qt][m] = MFMA(vf, pf[qt], o[qt][m]);
        }
    }

    // ---- epilogue: normalize, store cat[b][s][h*64+vd] ----
#pragma unroll
    for (int qt = 0; qt < 2; ++qt) {
        float inv = 1.f / l_r[qt];
        size_t cb = ((size_t)b * 2048 + qw + qt * 16 + lr) * 1024 + h * 64 + lg * 4;
#pragma unroll
        for (int m = 0; m < 4; ++m) {
            f16x4 ov;
#pragma unroll
            for (int r = 0; r < 4; ++r) ov[r] = (f16)(o[qt][m][r] * inv);
            *(f16x4*)&cat[cb + m * 16] = ov;
        }
    }
}

// ---------------------------------------------------------------------------
extern "C" void kernel_launch(void* const* d_in, const int* in_sizes, int n_in,
                              void* d_out, int out_size, void* d_ws, size_t ws_size,
                              hipStream_t stream) {
    const float* Q  = (const float*)d_in[0];
    const float* K  = (const float*)d_in[1];
    const float* V  = (const float*)d_in[2];
    const float* Wq = (const float*)d_in[3];
    const float* bq = (const float*)d_in[4];
    const float* Wk = (const float*)d_in[5];
    const float* bk = (const float*)d_in[6];
    const float* Wv = (const float*)d_in[7];
    const float* bv = (const float*)d_in[8];
    const float* Wo = (const float*)d_in[9];
    const float* bo = (const float*)d_in[10];

    char* ws = (char*)d_ws;
    size_t off = 0;
    auto alloc = [&](size_t bytes) {
        char* p = ws + off;
        off += (bytes + 255) & ~(size_t)255;
        return p;
    };
    f16* Qh  = (f16*)alloc(8192ULL * 1024 * 2);
    f16* Kh  = (f16*)alloc(8192ULL * 1024 * 2);
    f16* Vh  = (f16*)alloc(8192ULL * 1024 * 2);
    f16* WqT = (f16*)alloc(1024ULL * 1024 * 2);
    f16* WkT = (f16*)alloc(1024ULL * 1024 * 2);
    f16* WvT = (f16*)alloc(1024ULL * 1024 * 2);
    f16* WoT = (f16*)alloc(1024ULL * 1024 * 2);
    f16* qb  = (f16*)alloc(8192ULL * 1024 * 2);   // head-major [(b,h)][s][64]
    f16* kb  = (f16*)alloc(8192ULL * 1024 * 2);   // head-major [(b,h)][s][64]
    f16* vTb = (f16*)alloc(8192ULL * 1024 * 2);   // [(b,h)][vd][S]
    f16* cat = (f16*)alloc(8192ULL * 1024 * 2);   // [B*S][H*VS]

    k_convert<<<2048, 256, 0, stream>>>(Q, Qh, 8192 * 1024 / 4);
    k_convert<<<2048, 256, 0, stream>>>(K, Kh, 8192 * 1024 / 4);
    k_convert<<<2048, 256, 0, stream>>>(V, Vh, 8192 * 1024 / 4);
    k_transpose_w<<<4096, 256, 0, stream>>>(Wq, WqT, 0);
    k_transpose_w<<<4096, 256, 0, stream>>>(Wk, WkT, 0);
    k_transpose_w<<<4096, 256, 0, stream>>>(Wv, WvT, 0);
    k_transpose_w<<<4096, 256, 0, stream>>>(Wo, WoT, 1);

    dim3 gg(64, 8);
    k_gemm<0><<<gg, 256, 0, stream>>>(Qh, WqT, bq, qb);
    k_gemm<0><<<gg, 256, 0, stream>>>(Kh, WkT, bk, kb);
    k_gemm<1><<<gg, 256, 0, stream>>>(Vh, WvT, bv, vTb);

    k_attn<<<1024, 256, 0, stream>>>(qb, kb, vTb, cat);

    k_gemm<2><<<gg, 256, 0, stream>>>(cat, WoT, bo, d_out);
}

// Round 4
// 378.089 us; speedup vs baseline: 1.0743x; 1.0743x over previous
//
#include <hip/hip_runtime.h>
#include <hip/hip_fp16.h>
#include <cstdint>
#include <cstddef>

typedef _Float16 f16;
typedef _Float16 f16x8 __attribute__((ext_vector_type(8)));
typedef _Float16 f16x4 __attribute__((ext_vector_type(4)));
typedef float    f32x4 __attribute__((ext_vector_type(4)));

#define MFMA(a, b, c) __builtin_amdgcn_mfma_f32_16x16x32_f16(a, b, c, 0, 0, 0)

// B=4, S=2048, D=1024, H=16, KS=VS=64, O=1024.

__device__ __forceinline__ void gload_lds16(const f16* g, f16* l) {
    __builtin_amdgcn_global_load_lds(
        (const __attribute__((address_space(1))) void*)g,
        (__attribute__((address_space(3))) void*)l, 16, 0, 0);
}

// --------------------------- fp32 -> fp16 convert ---------------------------
__global__ void k_convert(const float* __restrict__ src, f16* __restrict__ dst, int n4) {
    int i = blockIdx.x * blockDim.x + threadIdx.x;
    int stride = gridDim.x * blockDim.x;
    for (; i < n4; i += stride) {
        float4 v = ((const float4*)src)[i];
        f16x4 h;
        h[0] = (f16)v.x; h[1] = (f16)v.y; h[2] = (f16)v.z; h[3] = (f16)v.w;
        ((f16x4*)dst)[i] = h;
    }
}

// ------------------- weight transpose + convert to fp16 ---------------------
// Tiled 64x64 LDS transpose; coalesced reads AND writes, 64x65 pad.
// mode 0: W[H=16][D=1024][KS=64] -> Wt[n=h*64+ks][d]
// mode 1: W[K=1024][N=1024]      -> Wt[n][k]
// grid: 256 blocks of 256 threads; block bx: nb = bx>>4 (out rows), db = bx&15.
__global__ void k_transpose_w(const float* __restrict__ W, f16* __restrict__ Wt, int mode) {
    __shared__ float T[64][65];
    const int bx = blockIdx.x;
    const int nb = bx >> 4, db = bx & 15;
    const int tid = threadIdx.x;
    const float* src = (mode == 0) ? (W + nb * 65536 + db * 4096)
                                   : (W + db * 65536 + nb * 64);
    const int rstride = (mode == 0) ? 64 : 1024;
    {
        int nn = tid & 63, d0 = tid >> 6;          // lanes cover nn: coalesced
#pragma unroll
        for (int p = 0; p < 16; ++p) {
            int dd = p * 4 + d0;
            T[dd][nn] = src[dd * rstride + nn];
        }
    }
    __syncthreads();
    {
        int dd = tid & 63, n0 = tid >> 6;          // lanes cover dd: coalesced out
#pragma unroll
        for (int p = 0; p < 16; ++p) {
            int nn = p * 4 + n0;
            Wt[(size_t)(nb * 64 + nn) * 1024 + db * 64 + dd] = (f16)T[dd][nn];
        }
    }
}

// ------------------------------- GEMM ---------------------------------------
// C[8192][1024] = A[8192][1024] * Bt[1024][1024]^T + bias
// MODE 0: f16 head-major  [(b*16+h)*2048 + s][64]
// MODE 1: f16 vT          [(b*16+h)*64 + d][2048]
// MODE 2: f32 row-major   [M][1024]
template <int MODE>
__global__ __launch_bounds__(256) void k_gemm(const f16* __restrict__ A,
                                              const f16* __restrict__ Bt,
                                              const float* __restrict__ bias,
                                              void* __restrict__ Cout) {
    __shared__ f16 As[128 * 32];   // linear (global_load_lds needs linear dest)
    __shared__ f16 Bs[128 * 32];
    const int tid = threadIdx.x;
    const int wid = tid >> 6, lane = tid & 63;
    const int wr = wid >> 1, wc = wid & 1;          // 2x2 waves, 64x64 out each
    const int lr = lane & 15, lg = lane >> 4;
    const int row0 = blockIdx.x * 128, col0 = blockIdx.y * 128;

    f32x4 acc[4][4];
#pragma unroll
    for (int m = 0; m < 4; ++m)
#pragma unroll
        for (int n = 0; n < 4; ++n) acc[m][n] = (f32x4){0.f, 0.f, 0.f, 0.f};

    const int c0 = tid, c1 = tid + 256;             // 16B chunk ids, 512 total
    const int r0 = c0 >> 2, cb0 = (c0 & 3) * 8;
    const int r1 = c1 >> 2, cb1 = (c1 & 3) * 8;

    for (int k0 = 0; k0 < 1024; k0 += 32) {
        __syncthreads();
        gload_lds16(&A[(size_t)(row0 + r0) * 1024 + k0 + cb0], &As[c0 * 8]);
        gload_lds16(&Bt[(size_t)(col0 + r0) * 1024 + k0 + cb0], &Bs[c0 * 8]);
        gload_lds16(&A[(size_t)(row0 + r1) * 1024 + k0 + cb1], &As[c1 * 8]);
        gload_lds16(&Bt[(size_t)(col0 + r1) * 1024 + k0 + cb1], &Bs[c1 * 8]);
        __syncthreads();
        f16x8 af[4], bf[4];
#pragma unroll
        for (int m = 0; m < 4; ++m) af[m] = *(const f16x8*)&As[(wr * 64 + m * 16 + lr) * 32 + lg * 8];
#pragma unroll
        for (int n = 0; n < 4; ++n) bf[n] = *(const f16x8*)&Bs[(wc * 64 + n * 16 + lr) * 32 + lg * 8];
#pragma unroll
        for (int m = 0; m < 4; ++m)
#pragma unroll
            for (int n = 0; n < 4; ++n) acc[m][n] = MFMA(af[m], bf[n], acc[m][n]);
    }

#pragma unroll
    for (int m = 0; m < 4; ++m) {
#pragma unroll
        for (int n = 0; n < 4; ++n) {
            int col = col0 + wc * 64 + n * 16 + lr;
            float bv = bias[col];
            if (MODE == 1) {
                // vT: addr contiguous in r -> vector store
                int row = row0 + wr * 64 + m * 16 + lg * 4;
                size_t a = ((size_t)((row >> 11) * 16 + (col >> 6)) * 64 + (col & 63)) * 2048 + (row & 2047);
                f16x4 ov;
#pragma unroll
                for (int r = 0; r < 4; ++r) ov[r] = (f16)(acc[m][n][r] + bv);
                *(f16x4*)&((f16*)Cout)[a] = ov;
            } else {
#pragma unroll
                for (int r = 0; r < 4; ++r) {
                    int row = row0 + wr * 64 + m * 16 + lg * 4 + r;
                    float v = acc[m][n][r] + bv;
                    if (MODE == 0) {
                        size_t a = ((size_t)((row >> 11) * 16 + (col >> 6)) * 2048 + (row & 2047)) * 64 + (col & 63);
                        ((f16*)Cout)[a] = (f16)v;
                    } else {
                        ((float*)Cout)[(size_t)row * 1024 + col] = v;
                    }
                }
            }
        }
    }
}

// ------------------------------ attention -----------------------------------
// No LDS. 1024 blocks (XCD-swizzled), 4 waves/block, 32 q-rows/wave.
// Permuted K-row loading puts S^T directly into PV B-fragment layout (P never
// leaves the lane). Register software pipeline (T14): V for tile kt issued at
// top of body; next tile's K prefetched into the K registers right after QK^T
// consumes them — both before the rescale branch, so loads are always in
// flight across the softmax (counted-vmcnt pipeline, never a full drain).
__global__ __launch_bounds__(256, 4) void k_attn(const f16* __restrict__ q,
                                                 const f16* __restrict__ k,
                                                 const f16* __restrict__ vT,
                                                 f16* __restrict__ cat) {
    // swizzle: 16 q-blocks of one (b,h) land on one XCD (K/V L2 locality)
    const int g = blockIdx.x;                 // 0..1023
    const int xcd = g & 7, i = g >> 3;        // i: 0..127
    const int bh = xcd + 8 * (i >> 4);        // bijective, 64 values
    const int qb = i & 15;
    const int b = bh >> 4, h = bh & 15;

    const int tid = threadIdx.x, wid = tid >> 6, lane = tid & 63;
    const int lr = lane & 15, lg = lane >> 4;
    const int qw = qb * 128 + wid * 32;       // this wave's first q-row

    const float SC = 0.125f * 1.44269504089f; // 1/sqrt(64) * log2(e)
    const float THR = 8.0f;                   // defer-max threshold (log2 units)

    // Q fragments (hoisted): B-operand, q-col = lr, d = half*32 + lg*8..
    f16x8 qf[2][2];
#pragma unroll
    for (int qt = 0; qt < 2; ++qt)
#pragma unroll
        for (int hf = 0; hf < 2; ++hf)
            qf[qt][hf] = *(const f16x8*)&q[((size_t)bh * 2048 + qw + qt * 16 + lr) * 64 + hf * 32 + lg * 8];

    // permuted K row base: tile t reads row kt + 8*(lr>>2) + 4*t + (lr&3)
    const f16* kbase = k + (size_t)bh * 2048 * 64 + (size_t)(8 * (lr >> 2) + (lr & 3)) * 64 + lg * 8;
    const f16* vbase = vT + (size_t)bh * 64 * 2048 + (size_t)lr * 2048 + lg * 8;

    f32x4 o[2][4];
#pragma unroll
    for (int qt = 0; qt < 2; ++qt)
#pragma unroll
        for (int m = 0; m < 4; ++m) o[qt][m] = (f32x4){0.f, 0.f, 0.f, 0.f};
    float m_r[2] = {-1.0e30f, -1.0e30f}, l_r[2] = {0.f, 0.f};

    // K register buffer: [t*2+half]; prologue loads tile 0
    f16x8 ka[4], vv[4];
    ka[0] = *(const f16x8*)(kbase);
    ka[1] = *(const f16x8*)(kbase + 32);
    ka[2] = *(const f16x8*)(kbase + 4 * 64);
    ka[3] = *(const f16x8*)(kbase + 4 * 64 + 32);

    for (int kt = 0; kt < 2048; kt += 32) {
        // ---- issue V loads for THIS tile (consumed at PV, end of body) ----
        vv[0] = *(const f16x8*)(vbase + kt);
        vv[1] = *(const f16x8*)(vbase + 16 * 2048 + kt);
        vv[2] = *(const f16x8*)(vbase + 32 * 2048 + kt);
        vv[3] = *(const f16x8*)(vbase + 48 * 2048 + kt);

        // ---- QK^T from ka: lane (lr,lg) reg r of tile t = S[kt+8lg+4t+r][qt*16+lr]
        f32x4 st[2][2];
#pragma unroll
        for (int t = 0; t < 2; ++t)
#pragma unroll
            for (int qt = 0; qt < 2; ++qt) {
                f32x4 z = (f32x4){0.f, 0.f, 0.f, 0.f};
                z = MFMA(ka[t * 2 + 0], qf[qt][0], z);
                z = MFMA(ka[t * 2 + 1], qf[qt][1], z);
                st[qt][t] = z;
            }

        // ---- prefetch NEXT tile's K into ka (dead after QK^T) ----
        {
            const f16* kn = kbase + (size_t)((kt + 32) & 2047) * 64;
            ka[0] = *(const f16x8*)(kn);
            ka[1] = *(const f16x8*)(kn + 32);
            ka[2] = *(const f16x8*)(kn + 4 * 64);
            ka[3] = *(const f16x8*)(kn + 4 * 64 + 32);
        }

        // ---- online softmax (log2 domain), stats per q-row = lr ----
        float tm[2];
#pragma unroll
        for (int qt = 0; qt < 2; ++qt) {
            float a0 = fmaxf(fmaxf(st[qt][0][0], st[qt][0][1]), fmaxf(st[qt][0][2], st[qt][0][3]));
            float a1 = fmaxf(fmaxf(st[qt][1][0], st[qt][1][1]), fmaxf(st[qt][1][2], st[qt][1][3]));
            float t0 = fmaxf(a0, a1);
            t0 = fmaxf(t0, __shfl_xor(t0, 16, 64));
            t0 = fmaxf(t0, __shfl_xor(t0, 32, 64));
            tm[qt] = t0 * SC;
        }
        bool need = (tm[0] > m_r[0] + THR) || (tm[1] > m_r[1] + THR);
        if (__any(need)) {
#pragma unroll
            for (int qt = 0; qt < 2; ++qt) {
                float m_new = fmaxf(m_r[qt], tm[qt]);
                float alpha = exp2f(m_r[qt] - m_new);
#pragma unroll
                for (int m = 0; m < 4; ++m)
#pragma unroll
                    for (int r = 0; r < 4; ++r) o[qt][m][r] *= alpha;
                l_r[qt] *= alpha;
                m_r[qt] = m_new;
            }
        }

        // ---- P = exp2(st*SC - m): already in B-frag layout, pack in-lane ----
        f16x8 pf[2];
#pragma unroll
        for (int qt = 0; qt < 2; ++qt) {
            float ps = 0.f;
            union { uint32_t u[4]; f16x8 v; } bb;
#pragma unroll
            for (int t = 0; t < 2; ++t)
#pragma unroll
                for (int pr = 0; pr < 2; ++pr) {
                    float p0 = exp2f(st[qt][t][2 * pr] * SC - m_r[qt]);
                    float p1 = exp2f(st[qt][t][2 * pr + 1] * SC - m_r[qt]);
                    ps += p0 + p1;
                    union { f16 h[2]; uint32_t u; } uu;
                    uu.h[0] = (f16)p0; uu.h[1] = (f16)p1;
                    bb.u[t * 2 + pr] = uu.u;    // B-frag word jp = 2t+pr (j = 4t+r)
                }
            ps += __shfl_xor(ps, 16, 64);
            ps += __shfl_xor(ps, 32, 64);
            l_r[qt] += ps;
            pf[qt] = bb.v;
        }

        // ---- PV: O^T[vd][q] += V^T[vd][kpos] * P^T[kpos][q] ----
#pragma unroll
        for (int m = 0; m < 4; ++m)
#pragma unroll
            for (int qt = 0; qt < 2; ++qt) o[qt][m] = MFMA(vv[m], pf[qt], o[qt][m]);
    }

    // ---- epilogue: normalize, store cat[b][s][h*64+vd] ----
#pragma unroll
    for (int qt = 0; qt < 2; ++qt) {
        float inv = 1.f / l_r[qt];
        size_t cb = ((size_t)b * 2048 + qw + qt * 16 + lr) * 1024 + h * 64 + lg * 4;
#pragma unroll
        for (int m = 0; m < 4; ++m) {
            f16x4 ov;
#pragma unroll
            for (int r = 0; r < 4; ++r) ov[r] = (f16)(o[qt][m][r] * inv);
            *(f16x4*)&cat[cb + m * 16] = ov;
        }
    }
}

// ---------------------------------------------------------------------------
extern "C" void kernel_launch(void* const* d_in, const int* in_sizes, int n_in,
                              void* d_out, int out_size, void* d_ws, size_t ws_size,
                              hipStream_t stream) {
    const float* Q  = (const float*)d_in[0];
    const float* K  = (const float*)d_in[1];
    const float* V  = (const float*)d_in[2];
    const float* Wq = (const float*)d_in[3];
    const float* bq = (const float*)d_in[4];
    const float* Wk = (const float*)d_in[5];
    const float* bk = (const float*)d_in[6];
    const float* Wv = (const float*)d_in[7];
    const float* bv = (const float*)d_in[8];
    const float* Wo = (const float*)d_in[9];
    const float* bo = (const float*)d_in[10];

    char* ws = (char*)d_ws;
    size_t off = 0;
    auto alloc = [&](size_t bytes) {
        char* p = ws + off;
        off += (bytes + 255) & ~(size_t)255;
        return p;
    };
    f16* Qh  = (f16*)alloc(8192ULL * 1024 * 2);
    f16* Kh  = (f16*)alloc(8192ULL * 1024 * 2);
    f16* Vh  = (f16*)alloc(8192ULL * 1024 * 2);
    f16* WqT = (f16*)alloc(1024ULL * 1024 * 2);
    f16* WkT = (f16*)alloc(1024ULL * 1024 * 2);
    f16* WvT = (f16*)alloc(1024ULL * 1024 * 2);
    f16* WoT = (f16*)alloc(1024ULL * 1024 * 2);
    f16* qb  = (f16*)alloc(8192ULL * 1024 * 2);   // head-major [(b,h)][s][64]
    f16* kb  = (f16*)alloc(8192ULL * 1024 * 2);   // head-major [(b,h)][s][64]
    f16* vTb = (f16*)alloc(8192ULL * 1024 * 2);   // [(b,h)][vd][S]
    f16* cat = (f16*)alloc(8192ULL * 1024 * 2);   // [B*S][H*VS]

    k_convert<<<2048, 256, 0, stream>>>(Q, Qh, 8192 * 1024 / 4);
    k_convert<<<2048, 256, 0, stream>>>(K, Kh, 8192 * 1024 / 4);
    k_convert<<<2048, 256, 0, stream>>>(V, Vh, 8192 * 1024 / 4);
    k_transpose_w<<<256, 256, 0, stream>>>(Wq, WqT, 0);
    k_transpose_w<<<256, 256, 0, stream>>>(Wk, WkT, 0);
    k_transpose_w<<<256, 256, 0, stream>>>(Wv, WvT, 0);
    k_transpose_w<<<256, 256, 0, stream>>>(Wo, WoT, 1);

    dim3 gg(64, 8);
    k_gemm<0><<<gg, 256, 0, stream>>>(Qh, WqT, bq, qb);
    k_gemm<0><<<gg, 256, 0, stream>>>(Kh, WkT, bk, kb);
    k_gemm<1><<<gg, 256, 0, stream>>>(Vh, WvT, bv, vTb);

    k_attn<<<1024, 256, 0, stream>>>(qb, kb, vTb, cat);

    k_gemm<2><<<gg, 256, 0, stream>>>(cat, WoT, bo, d_out);
}

// Round 6
// 268.419 us; speedup vs baseline: 1.5132x; 1.4086x over previous
//
#include <hip/hip_runtime.h>
#include <hip/hip_fp16.h>
#include <cstdint>
#include <cstddef>

typedef _Float16 f16;
typedef _Float16 f16x8 __attribute__((ext_vector_type(8)));
typedef _Float16 f16x4 __attribute__((ext_vector_type(4)));
typedef float    f32x4 __attribute__((ext_vector_type(4)));

#define MFMA(a, b, c) __builtin_amdgcn_mfma_f32_16x16x32_f16(a, b, c, 0, 0, 0)

// B=4, S=2048, D=1024, H=16, KS=VS=64, O=1024.

__device__ __forceinline__ void gload_lds16(const f16* g, f16* l) {
    __builtin_amdgcn_global_load_lds(
        (const __attribute__((address_space(1))) void*)g,
        (__attribute__((address_space(3))) void*)l, 16, 0, 0);
}

// --------------------------- fp32 -> fp16 convert ---------------------------
__global__ void k_convert(const float* __restrict__ src, f16* __restrict__ dst, int n4) {
    int i = blockIdx.x * blockDim.x + threadIdx.x;
    int stride = gridDim.x * blockDim.x;
    for (; i < n4; i += stride) {
        float4 v = ((const float4*)src)[i];
        f16x4 h;
        h[0] = (f16)v.x; h[1] = (f16)v.y; h[2] = (f16)v.z; h[3] = (f16)v.w;
        ((f16x4*)dst)[i] = h;
    }
}

// ------------------- weight transpose + convert to fp16 ---------------------
// Tiled 64x64 LDS transpose; coalesced reads AND writes.
// mode 0: W[H=16][D=1024][KS=64] -> Wt[n=h*64+ks][d]
// mode 1: W[K=1024][N=1024]      -> Wt[n][k]
__global__ void k_transpose_w(const float* __restrict__ W, f16* __restrict__ Wt, int mode) {
    __shared__ float T[64][65];
    const int bx = blockIdx.x;
    const int nb = bx >> 4, db = bx & 15;
    const int tid = threadIdx.x;
    const float* src = (mode == 0) ? (W + nb * 65536 + db * 4096)
                                   : (W + db * 65536 + nb * 64);
    const int rstride = (mode == 0) ? 64 : 1024;
    {
        int nn = tid & 63, d0 = tid >> 6;
#pragma unroll
        for (int p = 0; p < 16; ++p) {
            int dd = p * 4 + d0;
            T[dd][nn] = src[dd * rstride + nn];
        }
    }
    __syncthreads();
    {
        int dd = tid & 63, n0 = tid >> 6;
#pragma unroll
        for (int p = 0; p < 16; ++p) {
            int nn = p * 4 + n0;
            Wt[(size_t)(nb * 64 + nn) * 1024 + db * 64 + dd] = (f16)T[dd][nn];
        }
    }
}

// ------------------------------- GEMM ---------------------------------------
// C[8192][1024] = A[8192][1024] * Bt[1024][1024]^T + bias, then *scale.
// MODE 0: f16 head-major  [(b*16+h)][s][64]                     (q)
// MODE 1: f16 tile-packed V^T: [bh][tile=s>>5][vd][s&31]        (v)
// MODE 2: f32 row-major   [M][1024]                             (out)
// MODE 3: f16 tile-packed PERMUTED K: [bh][tile][h=d>>5][p][d&31], where
//         p = 16*((ks>>2)&1) + 4*(ks>>3) + (ks&3), ks = s&31  (B-frag row perm)
template <int MODE>
__global__ __launch_bounds__(256) void k_gemm(const f16* __restrict__ A,
                                              const f16* __restrict__ Bt,
                                              const float* __restrict__ bias,
                                              void* __restrict__ Cout,
                                              float scale) {
    __shared__ f16 As[128 * 32];   // linear (global_load_lds needs linear dest)
    __shared__ f16 Bs[128 * 32];
    const int tid = threadIdx.x;
    const int wid = tid >> 6, lane = tid & 63;
    const int wr = wid >> 1, wc = wid & 1;          // 2x2 waves, 64x64 out each
    const int lr = lane & 15, lg = lane >> 4;
    const int row0 = blockIdx.x * 128, col0 = blockIdx.y * 128;

    f32x4 acc[4][4];
#pragma unroll
    for (int m = 0; m < 4; ++m)
#pragma unroll
        for (int n = 0; n < 4; ++n) acc[m][n] = (f32x4){0.f, 0.f, 0.f, 0.f};

    const int c0 = tid, c1 = tid + 256;             // 16B chunk ids, 512 total
    const int r0 = c0 >> 2, cb0 = (c0 & 3) * 8;
    const int r1 = c1 >> 2, cb1 = (c1 & 3) * 8;

    for (int k0 = 0; k0 < 1024; k0 += 32) {
        __syncthreads();
        gload_lds16(&A[(size_t)(row0 + r0) * 1024 + k0 + cb0], &As[c0 * 8]);
        gload_lds16(&Bt[(size_t)(col0 + r0) * 1024 + k0 + cb0], &Bs[c0 * 8]);
        gload_lds16(&A[(size_t)(row0 + r1) * 1024 + k0 + cb1], &As[c1 * 8]);
        gload_lds16(&Bt[(size_t)(col0 + r1) * 1024 + k0 + cb1], &Bs[c1 * 8]);
        __syncthreads();
        f16x8 af[4], bf[4];
#pragma unroll
        for (int m = 0; m < 4; ++m) af[m] = *(const f16x8*)&As[(wr * 64 + m * 16 + lr) * 32 + lg * 8];
#pragma unroll
        for (int n = 0; n < 4; ++n) bf[n] = *(const f16x8*)&Bs[(wc * 64 + n * 16 + lr) * 32 + lg * 8];
#pragma unroll
        for (int m = 0; m < 4; ++m)
#pragma unroll
            for (int n = 0; n < 4; ++n) acc[m][n] = MFMA(af[m], bf[n], acc[m][n]);
    }

#pragma unroll
    for (int m = 0; m < 4; ++m) {
#pragma unroll
        for (int n = 0; n < 4; ++n) {
            int col = col0 + wc * 64 + n * 16 + lr;
            float bv = bias[col];
            int rowb = row0 + wr * 64 + m * 16 + lg * 4;    // base of 4 consecutive s
            if (MODE == 1) {
                int srow = rowb & 2047;
                size_t a = (size_t)((rowb >> 11) * 16 + (col >> 6)) * 131072
                         + (size_t)(srow >> 5) * 2048 + (size_t)(col & 63) * 32 + (srow & 31);
                f16x4 ov;
#pragma unroll
                for (int r = 0; r < 4; ++r) ov[r] = (f16)((acc[m][n][r] + bv) * scale);
                *(f16x4*)&((f16*)Cout)[a] = ov;
            } else if (MODE == 3) {
                int srow = rowb & 2047;
                int ks5 = srow & 31;                        // c = 0 at r=0 (lg*4 aligned)
                int p0 = ((ks5 >> 2) & 1) * 16 + (ks5 >> 3) * 4 + (ks5 & 3);
                size_t abase = (size_t)((rowb >> 11) * 16 + (col >> 6)) * 131072
                             + (size_t)(srow >> 5) * 2048 + (size_t)((col & 63) >> 5) * 1024
                             + (col & 31);
#pragma unroll
                for (int r = 0; r < 4; ++r)
                    ((f16*)Cout)[abase + (size_t)(p0 + r) * 32] = (f16)((acc[m][n][r] + bv) * scale);
            } else {
#pragma unroll
                for (int r = 0; r < 4; ++r) {
                    int row = rowb + r;
                    float v = (acc[m][n][r] + bv) * scale;
                    if (MODE == 0) {
                        size_t a = ((size_t)((row >> 11) * 16 + (col >> 6)) * 2048 + (row & 2047)) * 64 + (col & 63);
                        ((f16*)Cout)[a] = (f16)v;
                    } else {
                        ((float*)Cout)[(size_t)row * 1024 + col] = v;
                    }
                }
            }
        }
    }
}

// ------------------------------ attention -----------------------------------
// No LDS. 1024 blocks (XCD-swizzled), 4 waves/block, 32 q-rows/wave.
// K stored pre-permuted+tile-packed so each fragment load is a contiguous 1KB
// wave request and S^T lands directly in PV B-fragment layout. Steady-state
// iteration has ZERO cross-lane ops: lazy max (local check + __any, reduce
// only when triggered ~ first tile) and per-lane deferred l partial sums
// (reduced once in epilogue). Scale is pre-folded into q (log2 domain).
__global__ __launch_bounds__(256, 4) void k_attn(const f16* __restrict__ q,
                                                 const f16* __restrict__ k2,
                                                 const f16* __restrict__ v2,
                                                 f16* __restrict__ cat) {
    // swizzle: 16 q-blocks of one (b,h) land on one XCD (K/V L2 locality)
    const int g = blockIdx.x;                 // 0..1023
    const int xcd = g & 7, i = g >> 3;        // i: 0..127
    const int bh = xcd + 8 * (i >> 4);        // bijective, 64 values
    const int qb = i & 15;
    const int b = bh >> 4, h = bh & 15;

    const int tid = threadIdx.x, wid = tid >> 6, lane = tid & 63;
    const int lr = lane & 15, lg = lane >> 4;
    const int qw = qb * 128 + wid * 32;       // this wave's first q-row

    const float THR = 8.0f;                   // defer-max threshold (log2 units)

    // Q fragments (hoisted, pre-scaled by 1/8*log2e in the q GEMM)
    f16x8 qf[2][2];
#pragma unroll
    for (int qt = 0; qt < 2; ++qt)
#pragma unroll
        for (int hf = 0; hf < 2; ++hf)
            qf[qt][hf] = *(const f16x8*)&q[((size_t)bh * 2048 + qw + qt * 16 + lr) * 64 + hf * 32 + lg * 8];

    // K: [bh][tile][h][p][j]; lane reads p = t*16+lr, j = lg*8..; offsets t*512 + h*1024
    const f16* kbase = k2 + (size_t)bh * 131072 + lr * 32 + lg * 8;
    // V: [bh][tile][vd][ks]; lane reads vd = m*16+lr, ks = lg*8..; offset m*512
    const f16* vbase = v2 + (size_t)bh * 131072 + lr * 32 + lg * 8;

    f32x4 o[2][4];
#pragma unroll
    for (int qt = 0; qt < 2; ++qt)
#pragma unroll
        for (int m = 0; m < 4; ++m) o[qt][m] = (f32x4){0.f, 0.f, 0.f, 0.f};
    float m_r[2] = {-1.0e30f, -1.0e30f}, l_p[2] = {0.f, 0.f};

    // prologue: K tile 0. ka[t*2+h]
    f16x8 ka[4];
    ka[0] = *(const f16x8*)(kbase);
    ka[1] = *(const f16x8*)(kbase + 1024);
    ka[2] = *(const f16x8*)(kbase + 512);
    ka[3] = *(const f16x8*)(kbase + 1536);

    for (int tt = 0; tt < 64; ++tt) {
        // ---- V loads for THIS tile (contiguous 1KB wave requests) ----
        const f16* vt = vbase + tt * 2048;
        f16x8 vv[4];
        vv[0] = *(const f16x8*)(vt);
        vv[1] = *(const f16x8*)(vt + 512);
        vv[2] = *(const f16x8*)(vt + 1024);
        vv[3] = *(const f16x8*)(vt + 1536);

        // ---- QK^T: st[qt][t] reg r = S[kpos = tt*32 + 8lg + 4t + r][q = qt*16+lr]
        f32x4 st[2][2];
#pragma unroll
        for (int t = 0; t < 2; ++t)
#pragma unroll
            for (int qt = 0; qt < 2; ++qt) {
                f32x4 z = (f32x4){0.f, 0.f, 0.f, 0.f};
                z = MFMA(ka[t * 2 + 0], qf[qt][0], z);
                z = MFMA(ka[t * 2 + 1], qf[qt][1], z);
                st[qt][t] = z;
            }

        // ---- prefetch NEXT tile's K ----
        {
            const f16* kn = kbase + (size_t)((tt + 1) & 63) * 2048;
            ka[0] = *(const f16x8*)(kn);
            ka[1] = *(const f16x8*)(kn + 1024);
            ka[2] = *(const f16x8*)(kn + 512);
            ka[3] = *(const f16x8*)(kn + 1536);
        }

        // ---- lazy max: local check only; cross-lane reduce only if triggered
        float lm0 = fmaxf(fmaxf(fmaxf(st[0][0][0], st[0][0][1]), fmaxf(st[0][0][2], st[0][0][3])),
                          fmaxf(fmaxf(st[0][1][0], st[0][1][1]), fmaxf(st[0][1][2], st[0][1][3])));
        float lm1 = fmaxf(fmaxf(fmaxf(st[1][0][0], st[1][0][1]), fmaxf(st[1][0][2], st[1][0][3])),
                          fmaxf(fmaxf(st[1][1][0], st[1][1][1]), fmaxf(st[1][1][2], st[1][1][3])));
        if (__any((lm0 > m_r[0] + THR) || (lm1 > m_r[1] + THR))) {
            float lm[2] = {lm0, lm1};
#pragma unroll
            for (int qt = 0; qt < 2; ++qt) {
                float t0 = lm[qt];
                t0 = fmaxf(t0, __shfl_xor(t0, 16, 64));
                t0 = fmaxf(t0, __shfl_xor(t0, 32, 64));
                float m_new = fmaxf(m_r[qt], t0);
                float alpha = exp2f(m_r[qt] - m_new);
#pragma unroll
                for (int m = 0; m < 4; ++m)
#pragma unroll
                    for (int r = 0; r < 4; ++r) o[qt][m][r] *= alpha;
                l_p[qt] *= alpha;
                m_r[qt] = m_new;
            }
        }

        // ---- P = exp2(st - m): in B-frag layout already; per-lane partial sums
        f16x8 pf[2];
#pragma unroll
        for (int qt = 0; qt < 2; ++qt) {
            float ps = 0.f;
            union { uint32_t u[4]; f16x8 v; } bb;
#pragma unroll
            for (int t = 0; t < 2; ++t)
#pragma unroll
                for (int pr = 0; pr < 2; ++pr) {
                    float p0 = exp2f(st[qt][t][2 * pr] - m_r[qt]);
                    float p1 = exp2f(st[qt][t][2 * pr + 1] - m_r[qt]);
                    ps += p0 + p1;
                    union { f16 h2[2]; uint32_t u; } uu;
                    uu.h2[0] = (f16)p0; uu.h2[1] = (f16)p1;
                    bb.u[t * 2 + pr] = uu.u;
                }
            l_p[qt] += ps;
            pf[qt] = bb.v;
        }

        // ---- PV: O^T[vd][q] += V^T[vd][kpos] * P^T[kpos][q] ----
#pragma unroll
        for (int m = 0; m < 4; ++m)
#pragma unroll
            for (int qt = 0; qt < 2; ++qt) o[qt][m] = MFMA(vv[m], pf[qt], o[qt][m]);
    }

    // ---- epilogue: reduce l partial sums (only cross-lane ops in steady state)
#pragma unroll
    for (int qt = 0; qt < 2; ++qt) {
        float l = l_p[qt];
        l += __shfl_xor(l, 16, 64);
        l += __shfl_xor(l, 32, 64);
        float inv = 1.f / l;
        size_t cb = ((size_t)b * 2048 + qw + qt * 16 + lr) * 1024 + h * 64 + lg * 4;
#pragma unroll
        for (int m = 0; m < 4; ++m) {
            f16x4 ov;
#pragma unroll
            for (int r = 0; r < 4; ++r) ov[r] = (f16)(o[qt][m][r] * inv);
            *(f16x4*)&cat[cb + m * 16] = ov;
        }
    }
}

// ---------------------------------------------------------------------------
extern "C" void kernel_launch(void* const* d_in, const int* in_sizes, int n_in,
                              void* d_out, int out_size, void* d_ws, size_t ws_size,
                              hipStream_t stream) {
    const float* Q  = (const float*)d_in[0];
    const float* K  = (const float*)d_in[1];
    const float* V  = (const float*)d_in[2];
    const float* Wq = (const float*)d_in[3];
    const float* bq = (const float*)d_in[4];
    const float* Wk = (const float*)d_in[5];
    const float* bk = (const float*)d_in[6];
    const float* Wv = (const float*)d_in[7];
    const float* bv = (const float*)d_in[8];
    const float* Wo = (const float*)d_in[9];
    const float* bo = (const float*)d_in[10];

    char* ws = (char*)d_ws;
    size_t off = 0;
    auto alloc = [&](size_t bytes) {
        char* p = ws + off;
        off += (bytes + 255) & ~(size_t)255;
        return p;
    };
    f16* Qh  = (f16*)alloc(8192ULL * 1024 * 2);
    f16* Kh  = (f16*)alloc(8192ULL * 1024 * 2);
    f16* Vh  = (f16*)alloc(8192ULL * 1024 * 2);
    f16* WqT = (f16*)alloc(1024ULL * 1024 * 2);
    f16* WkT = (f16*)alloc(1024ULL * 1024 * 2);
    f16* WvT = (f16*)alloc(1024ULL * 1024 * 2);
    f16* WoT = (f16*)alloc(1024ULL * 1024 * 2);
    f16* qb  = (f16*)alloc(8192ULL * 1024 * 2);   // head-major [(b,h)][s][64]
    f16* kb2 = (f16*)alloc(8192ULL * 1024 * 2);   // [bh][tile][h][p][32] permuted
    f16* vb2 = (f16*)alloc(8192ULL * 1024 * 2);   // [bh][tile][vd][32]
    f16* cat = (f16*)alloc(8192ULL * 1024 * 2);   // [B*S][H*VS]

    k_convert<<<2048, 256, 0, stream>>>(Q, Qh, 8192 * 1024 / 4);
    k_convert<<<2048, 256, 0, stream>>>(K, Kh, 8192 * 1024 / 4);
    k_convert<<<2048, 256, 0, stream>>>(V, Vh, 8192 * 1024 / 4);
    k_transpose_w<<<256, 256, 0, stream>>>(Wq, WqT, 0);
    k_transpose_w<<<256, 256, 0, stream>>>(Wk, WkT, 0);
    k_transpose_w<<<256, 256, 0, stream>>>(Wv, WvT, 0);
    k_transpose_w<<<256, 256, 0, stream>>>(Wo, WoT, 1);

    const float SC = 0.125f * 1.44269504089f;   // 1/sqrt(64) * log2(e), folded into q
    dim3 gg(64, 8);
    k_gemm<0><<<gg, 256, 0, stream>>>(Qh, WqT, bq, qb, SC);
    k_gemm<3><<<gg, 256, 0, stream>>>(Kh, WkT, bk, kb2, 1.0f);
    k_gemm<1><<<gg, 256, 0, stream>>>(Vh, WvT, bv, vb2, 1.0f);

    k_attn<<<1024, 256, 0, stream>>>(qb, kb2, vb2, cat);

    k_gemm<2><<<gg, 256, 0, stream>>>(cat, WoT, bo, d_out, 1.0f);
}

// Round 8
// 243.177 us; speedup vs baseline: 1.6703x; 1.1038x over previous
//
#include <hip/hip_runtime.h>
#include <hip/hip_fp16.h>
#include <cstdint>
#include <cstddef>

typedef _Float16 f16;
typedef _Float16 f16x8 __attribute__((ext_vector_type(8)));
typedef _Float16 f16x4 __attribute__((ext_vector_type(4)));
typedef float    f32x4 __attribute__((ext_vector_type(4)));

#define MFMA(a, b, c) __builtin_amdgcn_mfma_f32_16x16x32_f16(a, b, c, 0, 0, 0)

// B=4, S=2048, D=1024, H=16, KS=VS=64, O=1024.

__device__ __forceinline__ void gload_lds16(const f16* g, f16* l) {
    __builtin_amdgcn_global_load_lds(
        (const __attribute__((address_space(1))) void*)g,
        (__attribute__((address_space(3))) void*)l, 16, 0, 0);
}

// ------------------- fp32 -> fp16 convert (Q,K,V fused) ----------------------
__global__ void k_convert3(const float* __restrict__ Q, const float* __restrict__ K,
                           const float* __restrict__ V, f16* __restrict__ Qh,
                           f16* __restrict__ Kh, f16* __restrict__ Vh) {
    const int seg = blockIdx.x >> 11;              // 0..2 (2048 blocks each)
    const int lb  = blockIdx.x & 2047;
    const float* src = seg == 0 ? Q : (seg == 1 ? K : V);
    f16* dst = seg == 0 ? Qh : (seg == 1 ? Kh : Vh);
    int i = lb * blockDim.x + threadIdx.x;
    for (; i < 2097152; i += 524288) {             // n4 = 8192*1024/4
        float4 v = ((const float4*)src)[i];
        f16x4 h;
        h[0] = (f16)v.x; h[1] = (f16)v.y; h[2] = (f16)v.z; h[3] = (f16)v.w;
        ((f16x4*)dst)[i] = h;
    }
}

// ---------------- weight transpose + convert to fp16 (all 4 fused) ----------
// widx 0,1,2: W[H=16][D=1024][KS=64] -> WT + widx*1M, rows n=h*64+ks, cols d
// widx 3:     Wo[K=1024][N=1024]     -> WoT[n][k]
__global__ void k_transpose_all(const float* __restrict__ Wq, const float* __restrict__ Wk,
                                const float* __restrict__ Wv, const float* __restrict__ Wo,
                                f16* __restrict__ WT, f16* __restrict__ WoT) {
    __shared__ float T[64][65];
    const int bx = blockIdx.x;
    const int widx = bx >> 8, sub = bx & 255;
    const int nb = sub >> 4, db = sub & 15;
    const int tid = threadIdx.x;
    const float* W = widx == 0 ? Wq : (widx == 1 ? Wk : (widx == 2 ? Wv : Wo));
    f16* Wt = (widx < 3) ? (WT + (size_t)widx * 1048576) : WoT;
    const float* src = (widx < 3) ? (W + nb * 65536 + db * 4096)
                                  : (W + db * 65536 + nb * 64);
    const int rstride = (widx < 3) ? 64 : 1024;
    {
        int nn = tid & 63, d0 = tid >> 6;
#pragma unroll
        for (int p = 0; p < 16; ++p) {
            int dd = p * 4 + d0;
            T[dd][nn] = src[dd * rstride + nn];
        }
    }
    __syncthreads();
    {
        int dd = tid & 63, n0 = tid >> 6;
#pragma unroll
        for (int p = 0; p < 16; ++p) {
            int nn = p * 4 + n0;
            Wt[(size_t)(nb * 64 + nn) * 1024 + db * 64 + dd] = (f16)T[dd][nn];
        }
    }
}

// --------------------------- fused q/k/v GEMM --------------------------------
// blockIdx.y 0..23: seg = y>>3 (0=q,1=k,2=v), col-block = y&7.
// seg 0: q head-major [(bh)][s][64], scaled by SC
// seg 1: K tile-packed PERMUTED [bh][tile][h=d>>5][p][d&31],
//        p = 16*((ks>>2)&1) + 4*(ks>>3) + (ks&3)
// seg 2: V^T tile-packed [bh][tile=s>>5][vd][s&31]
__global__ __launch_bounds__(256) void k_gemm_qkv(
    const f16* __restrict__ Qh, const f16* __restrict__ Kh, const f16* __restrict__ Vh,
    const f16* __restrict__ WT, const float* __restrict__ bq,
    const float* __restrict__ bk, const float* __restrict__ bv,
    f16* __restrict__ qout, f16* __restrict__ kout, f16* __restrict__ vout, float SC) {
    __shared__ f16 As[128 * 32];
    __shared__ f16 Bs[128 * 32];
    const int yy = blockIdx.y;
    const int seg = yy >> 3;
    const f16* A    = seg == 0 ? Qh : (seg == 1 ? Kh : Vh);
    const f16* Bt   = WT + (size_t)seg * 1048576;
    const float* bias = seg == 0 ? bq : (seg == 1 ? bk : bv);
    const float scale = seg == 0 ? SC : 1.0f;

    const int tid = threadIdx.x;
    const int wid = tid >> 6, lane = tid & 63;
    const int wr = wid >> 1, wc = wid & 1;
    const int lr = lane & 15, lg = lane >> 4;
    const int row0 = blockIdx.x * 128, col0 = (yy & 7) * 128;

    f32x4 acc[4][4];
#pragma unroll
    for (int m = 0; m < 4; ++m)
#pragma unroll
        for (int n = 0; n < 4; ++n) acc[m][n] = (f32x4){0.f, 0.f, 0.f, 0.f};

    const int c0 = tid, c1 = tid + 256;
    const int r0 = c0 >> 2, cb0 = (c0 & 3) * 8;
    const int r1 = c1 >> 2, cb1 = (c1 & 3) * 8;

    for (int k0 = 0; k0 < 1024; k0 += 32) {
        __syncthreads();
        gload_lds16(&A[(size_t)(row0 + r0) * 1024 + k0 + cb0], &As[c0 * 8]);
        gload_lds16(&Bt[(size_t)(col0 + r0) * 1024 + k0 + cb0], &Bs[c0 * 8]);
        gload_lds16(&A[(size_t)(row0 + r1) * 1024 + k0 + cb1], &As[c1 * 8]);
        gload_lds16(&Bt[(size_t)(col0 + r1) * 1024 + k0 + cb1], &Bs[c1 * 8]);
        __syncthreads();
        f16x8 af[4], bf[4];
#pragma unroll
        for (int m = 0; m < 4; ++m) af[m] = *(const f16x8*)&As[(wr * 64 + m * 16 + lr) * 32 + lg * 8];
#pragma unroll
        for (int n = 0; n < 4; ++n) bf[n] = *(const f16x8*)&Bs[(wc * 64 + n * 16 + lr) * 32 + lg * 8];
#pragma unroll
        for (int m = 0; m < 4; ++m)
#pragma unroll
            for (int n = 0; n < 4; ++n) acc[m][n] = MFMA(af[m], bf[n], acc[m][n]);
    }

#pragma unroll
    for (int m = 0; m < 4; ++m) {
#pragma unroll
        for (int n = 0; n < 4; ++n) {
            int col = col0 + wc * 64 + n * 16 + lr;
            float bv_ = bias[col];
            int rowb = row0 + wr * 64 + m * 16 + lg * 4;
            int srow = rowb & 2047;
            if (seg == 0) {
#pragma unroll
                for (int r = 0; r < 4; ++r) {
                    int row = rowb + r;
                    size_t a = ((size_t)((row >> 11) * 16 + (col >> 6)) * 2048 + (row & 2047)) * 64 + (col & 63);
                    qout[a] = (f16)((acc[m][n][r] + bv_) * scale);
                }
            } else if (seg == 1) {
                int ks5 = srow & 31;
                int p0 = ((ks5 >> 2) & 1) * 16 + (ks5 >> 3) * 4 + (ks5 & 3);
                size_t abase = (size_t)((rowb >> 11) * 16 + (col >> 6)) * 131072
                             + (size_t)(srow >> 5) * 2048 + (size_t)((col & 63) >> 5) * 1024
                             + (col & 31);
#pragma unroll
                for (int r = 0; r < 4; ++r)
                    kout[abase + (size_t)(p0 + r) * 32] = (f16)(acc[m][n][r] + bv_);
            } else {
                size_t a = (size_t)((rowb >> 11) * 16 + (col >> 6)) * 131072
                         + (size_t)(srow >> 5) * 2048 + (size_t)(col & 63) * 32 + (srow & 31);
                f16x4 ov;
#pragma unroll
                for (int r = 0; r < 4; ++r) ov[r] = (f16)(acc[m][n][r] + bv_);
                *(f16x4*)&vout[a] = ov;
            }
        }
    }
}

// ------------------------------ output GEMM ----------------------------------
__global__ __launch_bounds__(256) void k_gemm_out(const f16* __restrict__ A,
                                                  const f16* __restrict__ Bt,
                                                  const float* __restrict__ bias,
                                                  float* __restrict__ Cout) {
    __shared__ f16 As[128 * 32];
    __shared__ f16 Bs[128 * 32];
    const int tid = threadIdx.x;
    const int wid = tid >> 6, lane = tid & 63;
    const int wr = wid >> 1, wc = wid & 1;
    const int lr = lane & 15, lg = lane >> 4;
    const int row0 = blockIdx.x * 128, col0 = blockIdx.y * 128;

    f32x4 acc[4][4];
#pragma unroll
    for (int m = 0; m < 4; ++m)
#pragma unroll
        for (int n = 0; n < 4; ++n) acc[m][n] = (f32x4){0.f, 0.f, 0.f, 0.f};

    const int c0 = tid, c1 = tid + 256;
    const int r0 = c0 >> 2, cb0 = (c0 & 3) * 8;
    const int r1 = c1 >> 2, cb1 = (c1 & 3) * 8;

    for (int k0 = 0; k0 < 1024; k0 += 32) {
        __syncthreads();
        gload_lds16(&A[(size_t)(row0 + r0) * 1024 + k0 + cb0], &As[c0 * 8]);
        gload_lds16(&Bt[(size_t)(col0 + r0) * 1024 + k0 + cb0], &Bs[c0 * 8]);
        gload_lds16(&A[(size_t)(row0 + r1) * 1024 + k0 + cb1], &As[c1 * 8]);
        gload_lds16(&Bt[(size_t)(col0 + r1) * 1024 + k0 + cb1], &Bs[c1 * 8]);
        __syncthreads();
        f16x8 af[4], bf[4];
#pragma unroll
        for (int m = 0; m < 4; ++m) af[m] = *(const f16x8*)&As[(wr * 64 + m * 16 + lr) * 32 + lg * 8];
#pragma unroll
        for (int n = 0; n < 4; ++n) bf[n] = *(const f16x8*)&Bs[(wc * 64 + n * 16 + lr) * 32 + lg * 8];
#pragma unroll
        for (int m = 0; m < 4; ++m)
#pragma unroll
            for (int n = 0; n < 4; ++n) acc[m][n] = MFMA(af[m], bf[n], acc[m][n]);
    }

#pragma unroll
    for (int m = 0; m < 4; ++m) {
#pragma unroll
        for (int n = 0; n < 4; ++n) {
            int col = col0 + wc * 64 + n * 16 + lr;
            float bv = bias[col];
#pragma unroll
            for (int r = 0; r < 4; ++r) {
                int row = row0 + wr * 64 + m * 16 + lg * 4 + r;
                Cout[(size_t)row * 1024 + col] = acc[m][n][r] + bv;
            }
        }
    }
}

// ------------------------------ attention -----------------------------------
// No LDS. 1024 blocks (XCD-swizzled), 4 waves/block, 32 q-rows/wave.
// Tile-packed permuted K/V: fragment loads are contiguous 1KB wave requests,
// addressed by pointer increment + immediate offsets. S^T lands directly in
// PV B-fragment layout. Row-sum l computed by the MATRIX pipe via a ones-row
// MFMA (removes per-lane adds + epilogue shuffles). Lazy max via local check
// + __any; cross-lane traffic only when triggered (~first tile). exp2 via raw
// v_exp_f32; P->f16 via v_cvt_pkrtz. setprio(1) around MFMA clusters (T5).
__global__ __launch_bounds__(256, 4) void k_attn(const f16* __restrict__ q,
                                                 const f16* __restrict__ k2,
                                                 const f16* __restrict__ v2,
                                                 f16* __restrict__ cat) {
    const int g = blockIdx.x;
    const int xcd = g & 7, i = g >> 3;
    const int bh = xcd + 8 * (i >> 4);        // bijective, 64 values
    const int qb = i & 15;
    const int b = bh >> 4, h = bh & 15;

    const int tid = threadIdx.x, wid = tid >> 6, lane = tid & 63;
    const int lr = lane & 15, lg = lane >> 4;
    const int qw = qb * 128 + wid * 32;

    const float THR = 8.0f;

    f16x8 qf[2][2];
#pragma unroll
    for (int qt = 0; qt < 2; ++qt)
#pragma unroll
        for (int hf = 0; hf < 2; ++hf)
            qf[qt][hf] = *(const f16x8*)&q[((size_t)bh * 2048 + qw + qt * 16 + lr) * 64 + hf * 32 + lg * 8];

    const f16* kp = k2 + (size_t)bh * 131072 + lr * 32 + lg * 8;
    const f16* vp = v2 + (size_t)bh * 131072 + lr * 32 + lg * 8;

    f32x4 o[2][4], ol[2];
#pragma unroll
    for (int qt = 0; qt < 2; ++qt) {
#pragma unroll
        for (int m = 0; m < 4; ++m) o[qt][m] = (f32x4){0.f, 0.f, 0.f, 0.f};
        ol[qt] = (f32x4){0.f, 0.f, 0.f, 0.f};
    }
    float m_r[2] = {-1.0e30f, -1.0e30f};

    f16x8 ones;
#pragma unroll
    for (int j = 0; j < 8; ++j) ones[j] = (f16)1.0f;

    // prologue: K tile 0. ka[t*2+half]
    f16x8 ka[4];
    ka[0] = *(const f16x8*)(kp);
    ka[1] = *(const f16x8*)(kp + 1024);
    ka[2] = *(const f16x8*)(kp + 512);
    ka[3] = *(const f16x8*)(kp + 1536);

    for (int tt = 0; tt < 64; ++tt) {
        // V loads for THIS tile (contiguous 1KB wave requests; imm offsets)
        f16x8 vv0 = *(const f16x8*)(vp);
        f16x8 vv1 = *(const f16x8*)(vp + 512);
        f16x8 vv2 = *(const f16x8*)(vp + 1024);
        f16x8 vv3 = *(const f16x8*)(vp + 1536);
        vp += 2048;

        // QK^T: st[qt][t] reg r = S[kpos = tt*32 + 8lg + 4t + r][q = qt*16+lr]
        __builtin_amdgcn_s_setprio(1);
        f32x4 st[2][2];
#pragma unroll
        for (int t = 0; t < 2; ++t)
#pragma unroll
            for (int qt = 0; qt < 2; ++qt) {
                f32x4 z = (f32x4){0.f, 0.f, 0.f, 0.f};
                z = MFMA(ka[t * 2 + 0], qf[qt][0], z);
                z = MFMA(ka[t * 2 + 1], qf[qt][1], z);
                st[qt][t] = z;
            }
        __builtin_amdgcn_s_setprio(0);

        // prefetch NEXT tile's K (tail prefetch reads stay inside d_ws)
        kp += 2048;
        ka[0] = *(const f16x8*)(kp);
        ka[1] = *(const f16x8*)(kp + 1024);
        ka[2] = *(const f16x8*)(kp + 512);
        ka[3] = *(const f16x8*)(kp + 1536);

        // lazy max: max3-friendly local trees, cross-lane only when triggered
        float a0 = fmaxf(fmaxf(st[0][0][0], st[0][0][1]), st[0][0][2]);
        float b0 = fmaxf(fmaxf(st[0][0][3], st[0][1][0]), st[0][1][1]);
        float c0 = fmaxf(fmaxf(st[0][1][2], st[0][1][3]), a0);
        float lm0 = fmaxf(b0, c0);
        float a1 = fmaxf(fmaxf(st[1][0][0], st[1][0][1]), st[1][0][2]);
        float b1 = fmaxf(fmaxf(st[1][0][3], st[1][1][0]), st[1][1][1]);
        float c1 = fmaxf(fmaxf(st[1][1][2], st[1][1][3]), a1);
        float lm1 = fmaxf(b1, c1);
        if (__any((lm0 > m_r[0] + THR) || (lm1 > m_r[1] + THR))) {
            float lm[2] = {lm0, lm1};
#pragma unroll
            for (int qt = 0; qt < 2; ++qt) {
                float t0 = lm[qt];
                t0 = fmaxf(t0, __shfl_xor(t0, 16, 64));
                t0 = fmaxf(t0, __shfl_xor(t0, 32, 64));
                float m_new = fmaxf(m_r[qt], t0);
                float alpha = __builtin_amdgcn_exp2f(m_r[qt] - m_new);
#pragma unroll
                for (int m = 0; m < 4; ++m)
#pragma unroll
                    for (int r = 0; r < 4; ++r) o[qt][m][r] *= alpha;
#pragma unroll
                for (int r = 0; r < 4; ++r) ol[qt][r] *= alpha;
                m_r[qt] = m_new;
            }
        }

        // P = exp2(st - m), packed to f16 via v_cvt_pkrtz (B-frag layout)
        f16x8 pf[2];
#pragma unroll
        for (int qt = 0; qt < 2; ++qt) {
            union { uint32_t u[4]; f16x8 v; } bb;
#pragma unroll
            for (int t = 0; t < 2; ++t)
#pragma unroll
                for (int pr = 0; pr < 2; ++pr) {
                    float e0 = __builtin_amdgcn_exp2f(st[qt][t][2 * pr] - m_r[qt]);
                    float e1 = __builtin_amdgcn_exp2f(st[qt][t][2 * pr + 1] - m_r[qt]);
                    auto hp = __builtin_amdgcn_cvt_pkrtz(e0, e1);   // __fp16 x2
                    bb.u[t * 2 + pr] = __builtin_bit_cast(uint32_t, hp);
                }
            pf[qt] = bb.v;
        }

        // PV + ones-row l accumulation (matrix pipe does the row sums)
        __builtin_amdgcn_s_setprio(1);
#pragma unroll
        for (int qt = 0; qt < 2; ++qt) {
            o[qt][0] = MFMA(vv0, pf[qt], o[qt][0]);
            o[qt][1] = MFMA(vv1, pf[qt], o[qt][1]);
            o[qt][2] = MFMA(vv2, pf[qt], o[qt][2]);
            o[qt][3] = MFMA(vv3, pf[qt], o[qt][3]);
            ol[qt]   = MFMA(ones, pf[qt], ol[qt]);
        }
        __builtin_amdgcn_s_setprio(0);
    }

    // epilogue: l is lane-local (ones-MFMA put full row sum in every acc reg)
#pragma unroll
    for (int qt = 0; qt < 2; ++qt) {
        float inv = 1.f / ol[qt][0];
        size_t cb = ((size_t)b * 2048 + qw + qt * 16 + lr) * 1024 + h * 64 + lg * 4;
#pragma unroll
        for (int m = 0; m < 4; ++m) {
            f16x4 ov;
#pragma unroll
            for (int r = 0; r < 4; ++r) ov[r] = (f16)(o[qt][m][r] * inv);
            *(f16x4*)&cat[cb + m * 16] = ov;
        }
    }
}

// ---------------------------------------------------------------------------
extern "C" void kernel_launch(void* const* d_in, const int* in_sizes, int n_in,
                              void* d_out, int out_size, void* d_ws, size_t ws_size,
                              hipStream_t stream) {
    const float* Q  = (const float*)d_in[0];
    const float* K  = (const float*)d_in[1];
    const float* V  = (const float*)d_in[2];
    const float* Wq = (const float*)d_in[3];
    const float* bq = (const float*)d_in[4];
    const float* Wk = (const float*)d_in[5];
    const float* bk = (const float*)d_in[6];
    const float* Wv = (const float*)d_in[7];
    const float* bv = (const float*)d_in[8];
    const float* Wo = (const float*)d_in[9];
    const float* bo = (const float*)d_in[10];

    char* ws = (char*)d_ws;
    size_t off = 0;
    auto alloc = [&](size_t bytes) {
        char* p = ws + off;
        off += (bytes + 255) & ~(size_t)255;
        return p;
    };
    f16* Qh  = (f16*)alloc(8192ULL * 1024 * 2);
    f16* Kh  = (f16*)alloc(8192ULL * 1024 * 2);
    f16* Vh  = (f16*)alloc(8192ULL * 1024 * 2);
    f16* WT  = (f16*)alloc(3ULL * 1024 * 1024 * 2);   // WqT|WkT|WvT contiguous
    f16* WoT = (f16*)alloc(1024ULL * 1024 * 2);
    f16* qb  = (f16*)alloc(8192ULL * 1024 * 2);   // head-major [(b,h)][s][64]
    f16* kb2 = (f16*)alloc(8192ULL * 1024 * 2);   // [bh][tile][h][p][32] permuted
    f16* vb2 = (f16*)alloc(8192ULL * 1024 * 2);   // [bh][tile][vd][32]
    f16* cat = (f16*)alloc(8192ULL * 1024 * 2);   // [B*S][H*VS]

    k_convert3<<<6144, 256, 0, stream>>>(Q, K, V, Qh, Kh, Vh);
    k_transpose_all<<<1024, 256, 0, stream>>>(Wq, Wk, Wv, Wo, WT, WoT);

    const float SC = 0.125f * 1.44269504089f;   // 1/sqrt(64) * log2(e), folded into q
    k_gemm_qkv<<<dim3(64, 24), 256, 0, stream>>>(Qh, Kh, Vh, WT, bq, bk, bv,
                                                 qb, kb2, vb2, SC);

    k_attn<<<1024, 256, 0, stream>>>(qb, kb2, vb2, cat);

    k_gemm_out<<<dim3(64, 8), 256, 0, stream>>>(cat, WoT, bo, (float*)d_out);
}